// Round 1
// baseline (617.830 us; speedup 1.0000x reference)
//
#include <hip/hip_runtime.h>
#include <stdint.h>

#define B_ 2
#define S_ 2048
#define H_ 16
#define D_ 64
#define BS_ 128
#define NB_ 16
#define R_ 64

typedef __bf16 bf16x8 __attribute__((ext_vector_type(8)));
typedef float f32x4 __attribute__((ext_vector_type(4)));

__device__ __forceinline__ uint16_t f2bf(float f) {
    uint32_t u = __builtin_bit_cast(uint32_t, f);
    u += 0x7fffu + ((u >> 16) & 1u);   // RNE
    return (uint16_t)(u >> 16);
}

// One block per (b, n, h): 128x128 block-diagonal attention tile.
// LDS (48KB): k_lds [128][64] bf16 swizzled (QK phase) overlaid by
// p_lds [128][128] bf16 swizzled (PV phase); vt_lds [64][128] bf16 swizzled.
// Swizzle: byte ^= (row & 7) << 4  (fixes 16-way bank conflict on ds_read_b128).
__global__ __launch_bounds__(256, 2) void bb_diag(
    const float* __restrict__ q, const float* __restrict__ k,
    const float* __restrict__ v, const float* __restrict__ mask,
    float* __restrict__ out)
{
    __shared__ __align__(16) uint8_t smem[49152];
    uint8_t* const k_lds  = smem;          // 16KB, QK phase only
    uint8_t* const p_lds  = smem;          // 32KB, PV phase (overlays k_lds)
    uint8_t* const vt_lds = smem + 32768;  // 16KB

    const int tid  = (int)threadIdx.x;
    const int w    = tid >> 6;     // wave 0..3
    const int lane = tid & 63;
    const int g    = lane >> 4;    // lane group 0..3
    const int c    = lane & 15;

    const int blk = (int)blockIdx.x;
    const int h = blk & 15;
    const int n = (blk >> 4) & 15;
    const int b = blk >> 8;

    const int RS = H_ * D_;  // 1024 floats between consecutive sequence rows
    const size_t base = ((size_t)((b * S_ + n * BS_) * H_ + h)) * D_;
    const float* __restrict__ qg = q + base;
    const float* __restrict__ kg = k + base;
    const float* __restrict__ vg = v + base;
    float* __restrict__ og = out + base;

    // ---- stage K (row-major bf16) and V^T (d-major bf16), both swizzled ----
    #pragma unroll
    for (int it = 0; it < 8; ++it) {
        int i = it * 256 + tid;          // 2048 float4 tiles of 128x64
        int row = i >> 4;
        int c4  = i & 15;
        f32x4 kv = *(const f32x4*)(kg + (size_t)row * RS + c4 * 4);
        uint32_t lo = (uint32_t)f2bf(kv[0]) | ((uint32_t)f2bf(kv[1]) << 16);
        uint32_t hi = (uint32_t)f2bf(kv[2]) | ((uint32_t)f2bf(kv[3]) << 16);
        uint32_t ka = ((uint32_t)(row * 128 + c4 * 8)) ^ ((row & 7) << 4);
        uint2 pk; pk.x = lo; pk.y = hi;
        *(uint2*)(k_lds + ka) = pk;

        f32x4 vv = *(const f32x4*)(vg + (size_t)row * RS + c4 * 4);
        #pragma unroll
        for (int jj = 0; jj < 4; ++jj) {
            int j = (jj + c4) & 3;       // rotate to spread write banks
            int d = c4 * 4 + j;
            uint32_t va = ((uint32_t)(d * 256 + row * 2)) ^ ((d & 7) << 4);
            float vf = (j == 0) ? vv[0] : (j == 1) ? vv[1] : (j == 2) ? vv[2] : vv[3];
            *(uint16_t*)(vt_lds + va) = f2bf(vf);
        }
    }
    __syncthreads();

    // ---- Q fragments direct from global (each wave owns rows 32w..32w+31) ----
    bf16x8 qf[2][2];  // [mt][ks]
    #pragma unroll
    for (int mt = 0; mt < 2; ++mt) {
        int row = (2 * w + mt) * 16 + c;
        const float* qrow = qg + (size_t)row * RS;
        #pragma unroll
        for (int ks = 0; ks < 2; ++ks) {
            const float* p0 = qrow + ks * 32 + g * 8;
            f32x4 x0 = *(const f32x4*)p0;
            f32x4 x1 = *(const f32x4*)(p0 + 4);
            union { bf16x8 v8; uint16_t us[8]; } cv;
            cv.us[0] = f2bf(x0[0]); cv.us[1] = f2bf(x0[1]);
            cv.us[2] = f2bf(x0[2]); cv.us[3] = f2bf(x0[3]);
            cv.us[4] = f2bf(x1[0]); cv.us[5] = f2bf(x1[1]);
            cv.us[6] = f2bf(x1[2]); cv.us[7] = f2bf(x1[3]);
            qf[mt][ks] = cv.v8;
        }
    }

    // ---- QK^T: scores[32 rows][128 cols] per wave ----
    f32x4 acc[2][8];
    #pragma unroll
    for (int mt = 0; mt < 2; ++mt)
        #pragma unroll
        for (int nt = 0; nt < 8; ++nt)
            acc[mt][nt] = f32x4{0.f, 0.f, 0.f, 0.f};

    #pragma unroll
    for (int ks = 0; ks < 2; ++ks) {
        #pragma unroll
        for (int nt = 0; nt < 8; ++nt) {
            int krow = nt * 16 + c;
            uint32_t ka = ((uint32_t)(krow * 128 + ks * 64 + g * 16)) ^ ((krow & 7) << 4);
            bf16x8 bfr = *(const bf16x8*)(k_lds + ka);
            acc[0][nt] = __builtin_amdgcn_mfma_f32_16x16x32_bf16(qf[0][ks], bfr, acc[0][nt], 0, 0, 0);
            acc[1][nt] = __builtin_amdgcn_mfma_f32_16x16x32_bf16(qf[1][ks], bfr, acc[1][nt], 0, 0, 0);
        }
    }
    __syncthreads();  // all K-LDS reads complete before P overlays the region

    // ---- scale + mask + softmax (full row in registers), write P (bf16) ----
    const float* mb = mask + ((size_t)(b * H_ + h) * S_ + n * BS_) * S_ + (size_t)(n * BS_);
    float rcp_s[2][4];
    #pragma unroll
    for (int mt = 0; mt < 2; ++mt) {
        #pragma unroll
        for (int j = 0; j < 4; ++j) {
            int row = (2 * w + mt) * 16 + g * 4 + j;  // D-layout row for reg j
            const float* mrow = mb + (size_t)row * S_;
            float s[8];
            float mx = -1e30f;
            #pragma unroll
            for (int nt = 0; nt < 8; ++nt) {
                s[nt] = acc[mt][nt][j] * 0.125f + mrow[nt * 16 + c];
                mx = fmaxf(mx, s[nt]);
            }
            #pragma unroll
            for (int t = 1; t < 16; t <<= 1) mx = fmaxf(mx, __shfl_xor(mx, t));
            float sum = 0.f;
            #pragma unroll
            for (int nt = 0; nt < 8; ++nt) {
                float p = __expf(s[nt] - mx);
                sum += p;
                uint32_t pa = ((uint32_t)(row * 256 + (nt * 16 + c) * 2)) ^ ((row & 7) << 4);
                *(uint16_t*)(p_lds + pa) = f2bf(p);
            }
            #pragma unroll
            for (int t = 1; t < 16; t <<= 1) sum += __shfl_xor(sum, t);
            rcp_s[mt][j] = 1.0f / sum;
        }
    }
    __syncthreads();

    // ---- PV: out[32 rows][64 d] per wave ----
    f32x4 acc2[2][4];
    #pragma unroll
    for (int mt = 0; mt < 2; ++mt)
        #pragma unroll
        for (int nt = 0; nt < 4; ++nt)
            acc2[mt][nt] = f32x4{0.f, 0.f, 0.f, 0.f};

    #pragma unroll
    for (int kk = 0; kk < 4; ++kk) {
        bf16x8 af[2];
        #pragma unroll
        for (int mt = 0; mt < 2; ++mt) {
            int prow = (2 * w + mt) * 16 + c;
            uint32_t pa = ((uint32_t)(prow * 256 + kk * 64 + g * 16)) ^ ((prow & 7) << 4);
            af[mt] = *(const bf16x8*)(p_lds + pa);
        }
        #pragma unroll
        for (int nt = 0; nt < 4; ++nt) {
            int drow = nt * 16 + c;
            uint32_t va = ((uint32_t)(drow * 256 + kk * 64 + g * 16)) ^ ((drow & 7) << 4);
            bf16x8 bfr = *(const bf16x8*)(vt_lds + va);
            acc2[0][nt] = __builtin_amdgcn_mfma_f32_16x16x32_bf16(af[0], bfr, acc2[0][nt], 0, 0, 0);
            acc2[1][nt] = __builtin_amdgcn_mfma_f32_16x16x32_bf16(af[1], bfr, acc2[1][nt], 0, 0, 0);
        }
    }

    // ---- epilogue: normalize; fuse the exact global-attn add (+v) for n==0 ----
    #pragma unroll
    for (int mt = 0; mt < 2; ++mt) {
        #pragma unroll
        for (int j = 0; j < 4; ++j) {
            int row = (2 * w + mt) * 16 + g * 4 + j;
            float rc = rcp_s[mt][j];
            #pragma unroll
            for (int nt = 0; nt < 4; ++nt) {
                int col = nt * 16 + c;
                float val = acc2[mt][nt][j] * rc;
                if (n == 0) val += vg[(size_t)row * RS + col];  // out[:, :G] += v[:, :G]
                og[(size_t)row * RS + col] = val;
            }
        }
    }
}

// Random part: softmax row-sums are exactly 1, so out[:, rand_idx] += v[rand_idx]
// (atomicAdd handles duplicate indices -> multiplicity).
__global__ __launch_bounds__(256) void bb_rand_add(
    const float* __restrict__ v, const int* __restrict__ ridx,
    float* __restrict__ out)
{
    int t = (int)(blockIdx.x * 256u + threadIdx.x);  // B*R*H*D = 131072
    int d = t & 63;
    int h = (t >> 6) & 15;
    int r = (t >> 10) & 63;
    int b = t >> 16;
    int s = ridx[r];
    size_t off = ((size_t)((b * S_ + s) * H_ + h)) * D_ + d;
    atomicAdd(out + off, v[off]);
}

extern "C" void kernel_launch(void* const* d_in, const int* in_sizes, int n_in,
                              void* d_out, int out_size, void* d_ws, size_t ws_size,
                              hipStream_t stream) {
    const float* q    = (const float*)d_in[0];
    const float* k    = (const float*)d_in[1];
    const float* v    = (const float*)d_in[2];
    const float* mask = (const float*)d_in[3];
    const int*   ridx = (const int*)d_in[4];
    float* out = (float*)d_out;

    bb_diag<<<dim3(B_ * NB_ * H_), dim3(256), 0, stream>>>(q, k, v, mask, out);
    bb_rand_add<<<dim3((B_ * R_ * H_ * D_) / 256), dim3(256), 0, stream>>>(v, ridx, out);
}

// Round 2
// 613.239 us; speedup vs baseline: 1.0075x; 1.0075x over previous
//
#include <hip/hip_runtime.h>
#include <stdint.h>

#define B_ 2
#define S_ 2048
#define H_ 16
#define D_ 64
#define BS_ 128
#define NB_ 16
#define R_ 64

typedef __bf16 bf16x8 __attribute__((ext_vector_type(8)));
typedef __bf16 bf16x4 __attribute__((ext_vector_type(4)));
typedef float  f32x4  __attribute__((ext_vector_type(4)));

// One block per (b, n, h, half): 64 q-rows x 128 k-cols of the block-diagonal
// attention. 4 waves x 16 q-rows. Grid = 1024 -> 4 blocks/CU (16 waves/CU).
// LDS 33KB: k_lds[128][64]bf16 (16KB, QK phase) overlaid by p_lds[64][128]bf16
// (16KB, PV phase); vt_lds[64][128]bf16 (16KB); cnt[64] int.
// Swizzle byte ^= (row&7)<<4 kills the stride-128B/256B bank conflicts.
// Global-attn part is exactly out[:, :G] += v[:, :G] (softmax rows sum to 1,
// gv has no s index) -> fused as +v for n==0 (G == BS == 128).
// Random part is exactly out[:, ridx] += v[ridx] (rowsum == 1) -> fused via
// per-block multiplicity counts (each out row owned by exactly one block).
__global__ __launch_bounds__(256, 4) void bb_diag(
    const float* __restrict__ q, const float* __restrict__ k,
    const float* __restrict__ v, const float* __restrict__ mask,
    const int* __restrict__ ridx, float* __restrict__ out)
{
    __shared__ __align__(16) uint8_t smem[33024];
    uint8_t* const k_lds  = smem;          // 16KB, QK phase
    uint8_t* const p_lds  = smem;          // 16KB, PV phase (overlays k_lds)
    uint8_t* const vt_lds = smem + 16384;  // 16KB
    int* const cnt = (int*)(smem + 32768); // 64 ints

    const int tid  = (int)threadIdx.x;
    const int w    = tid >> 6;     // wave 0..3
    const int lane = tid & 63;
    const int g    = lane >> 4;    // lane group 0..3
    const int c    = lane & 15;

    const int blk  = (int)blockIdx.x;
    const int half = blk >> 9;         // twins (half 0/1) are 512 apart ->
    const int rest = blk & 511;        // same XCD -> shared K/V tile hits L2
    const int h = rest & 15;
    const int n = (rest >> 4) & 15;
    const int b = rest >> 8;

    const int RS = H_ * D_;  // 1024 floats between consecutive seq rows
    const size_t base = ((size_t)((b * S_ + n * BS_) * H_ + h)) * D_;
    const float* __restrict__ qg = q + base;
    const float* __restrict__ kg = k + base;
    const float* __restrict__ vg = v + base;
    float* __restrict__ og = out + base;

    if (tid < 64) cnt[tid] = 0;

    // ---- stage K (row-major bf16) and V^T (d-major bf16), swizzled ----
    #pragma unroll
    for (int it = 0; it < 8; ++it) {
        int i   = it * 256 + tid;    // 2048 f32x4 tiles of 128x64
        int row = i >> 4;
        int c4  = i & 15;
        f32x4 kv = *(const f32x4*)(kg + (size_t)row * RS + c4 * 4);
        bf16x4 kb;
        kb[0] = (__bf16)kv[0]; kb[1] = (__bf16)kv[1];
        kb[2] = (__bf16)kv[2]; kb[3] = (__bf16)kv[3];
        uint32_t ka = ((uint32_t)(row * 128 + c4 * 8)) ^ ((row & 7) << 4);
        *(bf16x4*)(k_lds + ka) = kb;

        f32x4 vv = *(const f32x4*)(vg + (size_t)row * RS + c4 * 4);
        #pragma unroll
        for (int jj = 0; jj < 4; ++jj) {
            int j = (jj + c4) & 3;   // rotate to spread write banks
            int d = c4 * 4 + j;
            uint32_t va = ((uint32_t)(d * 256 + row * 2)) ^ ((d & 7) << 4);
            float vf = (j == 0) ? vv[0] : (j == 1) ? vv[1] : (j == 2) ? vv[2] : vv[3];
            *(__bf16*)(vt_lds + va) = (__bf16)vf;
        }
    }

    // ---- prefetch Q fragments (overlaps staging latency) ----
    bf16x8 qf[2];
    {
        int row_l = w * 16 + c;
        const float* qrow = qg + (size_t)(half * 64 + row_l) * RS;
        #pragma unroll
        for (int ks = 0; ks < 2; ++ks) {
            f32x4 x0 = *(const f32x4*)(qrow + ks * 32 + g * 8);
            f32x4 x1 = *(const f32x4*)(qrow + ks * 32 + g * 8 + 4);
            union { bf16x8 v8; __bf16 e[8]; } cv;
            #pragma unroll
            for (int j = 0; j < 4; ++j) { cv.e[j] = (__bf16)x0[j]; cv.e[4 + j] = (__bf16)x1[j]; }
            qf[ks] = cv.v8;
        }
    }

    // ---- prefetch mask (overlaps staging latency; softmax has no gmem) ----
    float m[4][8];
    {
        const float* mb = mask + ((size_t)(b * H_ + h) * S_ + n * BS_ + half * 64 + w * 16) * S_
                               + (size_t)(n * BS_);
        #pragma unroll
        for (int j = 0; j < 4; ++j) {
            const float* mrow = mb + (size_t)(g * 4 + j) * S_;
            #pragma unroll
            for (int nt = 0; nt < 8; ++nt) m[j][nt] = mrow[nt * 16 + c];
        }
    }
    __syncthreads();

    // rand-index multiplicities for this block's 64 rows (ordered by barriers)
    if (tid < 64) {
        int s = ridx[tid];
        int lo = n * BS_ + half * 64;
        if (s >= lo && s < lo + 64) atomicAdd(&cnt[s - lo], 1);
    }

    // ---- QK^T: scores[16 rows][128 cols] per wave ----
    f32x4 acc[8];
    #pragma unroll
    for (int nt = 0; nt < 8; ++nt) acc[nt] = f32x4{0.f, 0.f, 0.f, 0.f};
    #pragma unroll
    for (int ks = 0; ks < 2; ++ks) {
        #pragma unroll
        for (int nt = 0; nt < 8; ++nt) {
            int krow = nt * 16 + c;
            uint32_t ka = ((uint32_t)(krow * 128 + ks * 64 + g * 16)) ^ ((krow & 7) << 4);
            bf16x8 bfr = *(const bf16x8*)(k_lds + ka);
            acc[nt] = __builtin_amdgcn_mfma_f32_16x16x32_bf16(qf[ks], bfr, acc[nt], 0, 0, 0);
        }
    }
    __syncthreads();  // K-LDS reads complete before P overlays the region

    // ---- scale + mask + softmax (row in registers), write P (bf16) ----
    float rcp_s[4];
    #pragma unroll
    for (int j = 0; j < 4; ++j) {
        int row = w * 16 + g * 4 + j;   // local q-row 0..63 (D-layout)
        float s[8];
        float mx = -1e30f;
        #pragma unroll
        for (int nt = 0; nt < 8; ++nt) {
            s[nt] = acc[nt][j] * 0.125f + m[j][nt];
            mx = fmaxf(mx, s[nt]);
        }
        #pragma unroll
        for (int t = 1; t < 16; t <<= 1) mx = fmaxf(mx, __shfl_xor(mx, t));
        float sum = 0.f;
        #pragma unroll
        for (int nt = 0; nt < 8; ++nt) {
            float p = __expf(s[nt] - mx);
            sum += p;
            uint32_t pa = ((uint32_t)(row * 256 + (nt * 16 + c) * 2)) ^ ((row & 7) << 4);
            *(__bf16*)(p_lds + pa) = (__bf16)p;
        }
        #pragma unroll
        for (int t = 1; t < 16; t <<= 1) sum += __shfl_xor(sum, t);
        rcp_s[j] = 1.0f / sum;
    }
    __syncthreads();

    // ---- PV: out[16 rows][64 d] per wave ----
    f32x4 acc2[4];
    #pragma unroll
    for (int nt = 0; nt < 4; ++nt) acc2[nt] = f32x4{0.f, 0.f, 0.f, 0.f};
    #pragma unroll
    for (int kk = 0; kk < 4; ++kk) {
        int prow = w * 16 + c;
        uint32_t pa = ((uint32_t)(prow * 256 + kk * 64 + g * 16)) ^ ((prow & 7) << 4);
        bf16x8 af = *(const bf16x8*)(p_lds + pa);
        #pragma unroll
        for (int nt = 0; nt < 4; ++nt) {
            int drow = nt * 16 + c;
            uint32_t va = ((uint32_t)(drow * 256 + kk * 64 + g * 16)) ^ ((drow & 7) << 4);
            bf16x8 bfr = *(const bf16x8*)(vt_lds + va);
            acc2[nt] = __builtin_amdgcn_mfma_f32_16x16x32_bf16(af, bfr, acc2[nt], 0, 0, 0);
        }
    }

    // ---- epilogue: normalize; fuse global-attn (+v, n==0) and rand (+mult*v)
    #pragma unroll
    for (int j = 0; j < 4; ++j) {
        int r_l = w * 16 + g * 4 + j;      // local row 0..63
        int r_t = half * 64 + r_l;         // row within the 128-row tile
        float rc = rcp_s[j];
        float coef = (float)(cnt[r_l] + ((n == 0) ? 1 : 0));
        #pragma unroll
        for (int nt = 0; nt < 4; ++nt) {
            int col = nt * 16 + c;
            float val = acc2[nt][j] * rc;
            if (coef != 0.f) val += coef * vg[(size_t)r_t * RS + col];
            og[(size_t)r_t * RS + col] = val;
        }
    }
}

extern "C" void kernel_launch(void* const* d_in, const int* in_sizes, int n_in,
                              void* d_out, int out_size, void* d_ws, size_t ws_size,
                              hipStream_t stream) {
    const float* q    = (const float*)d_in[0];
    const float* k    = (const float*)d_in[1];
    const float* v    = (const float*)d_in[2];
    const float* mask = (const float*)d_in[3];
    const int*   ridx = (const int*)d_in[4];
    float* out = (float*)d_out;

    bb_diag<<<dim3(B_ * NB_ * H_ * 2), dim3(256), 0, stream>>>(q, k, v, mask, ridx, out);
}